// Round 6
// baseline (321.610 us; speedup 1.0000x reference)
//
#include <hip/hip_runtime.h>

#define BS   64
#define NQ   3000
#define NC   256
#define FH   100
#define FW   100
#define TOPK 1500

// ---------------- Kernel A: scores[b,q] = max_c class[b,q,c] ----------------
// One row (64 float4) per wave-iteration; 4 rows per wave for 4 outstanding
// loads. Lane l reads float4 l of each row (1 KB coalesced per instruction).
// Memory-bound at ~31 us floor (196.6 MB @ 6.3 TB/s) — at roofline.
__global__ __launch_bounds__(256) void scores_kernel(const float4* __restrict__ cls,
                                                     float* __restrict__ scores) {
    const int tid  = threadIdx.x;
    const int lane = tid & 63;
    const int wave = tid >> 6;
    const int row0 = blockIdx.x * 16 + wave * 4;  // 16 rows per block, grid exact
    const float4* p = cls + (size_t)row0 * (NC / 4) + lane;
    float4 a = p[0], b = p[64], c = p[128], d = p[192];
    float m0 = fmaxf(fmaxf(a.x, a.y), fmaxf(a.z, a.w));
    float m1 = fmaxf(fmaxf(b.x, b.y), fmaxf(b.z, b.w));
    float m2 = fmaxf(fmaxf(c.x, c.y), fmaxf(c.z, c.w));
    float m3 = fmaxf(fmaxf(d.x, d.y), fmaxf(d.z, d.w));
#pragma unroll
    for (int off = 32; off > 0; off >>= 1) {
        m0 = fmaxf(m0, __shfl_xor(m0, off, 64));
        m1 = fmaxf(m1, __shfl_xor(m1, off, 64));
        m2 = fmaxf(m2, __shfl_xor(m2, off, 64));
        m3 = fmaxf(m3, __shfl_xor(m3, off, 64));
    }
    if (lane < 4) {
        float m = (lane == 0) ? m0 : (lane == 1) ? m1 : (lane == 2) ? m2 : m3;
        scores[row0 + lane] = m;
    }
}

// Wave-aggregated LDS histogram add: scores concentrate (max of 256 uniforms),
// so most waves have all lanes hitting ONE bin -> 64-way same-address atomic
// serialization. Loop over distinct bins; one leader atomic per distinct bin.
__device__ __forceinline__ void agg_add(int* __restrict__ hrow, unsigned bin, bool pr) {
    unsigned long long act = __ballot(pr);
    const int lane = threadIdx.x & 63;
    while (act) {
        const int leader = __ffsll((unsigned long long)act) - 1;
        const unsigned lbin = (unsigned)__shfl((int)bin, leader, 64);
        const unsigned long long same = __ballot(pr && (bin == lbin));
        if (pr && (bin == lbin) && lane == leader)
            atomicAdd(&hrow[lbin], (int)__popcll(same));
        act &= ~same;
    }
}

// ---------------- Kernel B: per-(batch,slice) select + raster ----------------
// Best-measured structure (R5: 297.8us): grid (NSPLIT, BS) = 512 blocks; each
// block redundantly radix-selects the per-batch threshold + scalar tie cutoff,
// then scatter-rasters ONLY its NQ/NSPLIT query slice into a private LDS
// bitmap -> partial plane. R6 micro-pack on the select phase only:
//   - pass-0 histogram fused into the score-load loop (no prefix condition)
//   - ballot-aggregated histogram adds (concentrated bins -> 1 atomic/wave)
//   - double-buffered hist: idle upper threads zero next pass's buffer during
//     the bin-scan -> 11 barriers instead of 16, no zero loops on the path
#define NSPLIT 8
#define NTM    512  // 8 waves
#define QSLICE ((NQ + NSPLIT - 1) / NSPLIT)  // 375

__global__ __launch_bounds__(NTM) void raster_kernel(const float4* __restrict__ coord,
                                                     const int* __restrict__ vfs,
                                                     const float* __restrict__ scores,
                                                     unsigned* __restrict__ pcov) {
    __shared__ __align__(16) unsigned su[NQ];  // score bits (positive: uint order == float order)
    __shared__ int      hist[2][8][256];  // double-buffered per-wave histograms
    __shared__ unsigned cov[FH * 4];      // 100 rows x 128-bit coverage (this slice)
    __shared__ int      eqlist[NQ];       // 24-bit-prefix candidates (from p==2 scan)
    __shared__ int      wave_sum[4];
    __shared__ int      s_selbin, s_K, s_c24, s_qcut;

    const int part = blockIdx.x;       // slice within batch
    const int b    = blockIdx.y;       // batch
    const int tid  = threadIdx.x;
    const int wid  = tid >> 6;

    for (int i = tid; i < 8 * 256; i += NTM) ((int*)hist[0])[i] = 0;
    for (int i = tid; i < FH * 4; i += NTM) cov[i] = 0u;
    if (tid == 0) s_c24 = 0;
    __syncthreads();

    // ---- fused: vectorized score load + pass-0 histogram (all values) ----
    {
        const uint4* sp = (const uint4*)(scores + b * NQ);
        uint4* sd = (uint4*)su;
        int* hrow = hist[0][wid];
        for (int i = tid; i < NQ / 4; i += NTM) {
            uint4 v4 = sp[i];
            sd[i] = v4;
            agg_add(hrow, v4.x >> 24, true);
            agg_add(hrow, v4.y >> 24, true);
            agg_add(hrow, v4.z >> 24, true);
            agg_add(hrow, v4.w >> 24, true);
        }
    }
    __syncthreads();

    // ---- byte-wise radix descent ----
    unsigned prefix = 0, pmask = 0;
    int K = TOPK;
#pragma unroll
    for (int p = 0; p < 4; ++p) {
        const int shift = 24 - 8 * p;
        const int hb    = p & 1;
        // phase A: tid<256 bin-scan hist[hb]; tid>=256 zero hist[hb^1]
        int x = 0, hx = 0, bin = 0;
        if (tid < 256) {
            bin = 255 - tid;
            const int(*H)[256] = hist[hb];
            hx = H[0][bin] + H[1][bin] + H[2][bin] + H[3][bin] +
                 H[4][bin] + H[5][bin] + H[6][bin] + H[7][bin];
            x = hx;
#pragma unroll
            for (int off = 1; off < 64; off <<= 1) {
                int y = __shfl_up(x, off, 64);
                if ((tid & 63) >= off) x += y;
            }
            if ((tid & 63) == 63) wave_sum[tid >> 6] = x;
        } else if (p < 3) {
            for (int i = tid - 256; i < 8 * 256; i += 256) ((int*)hist[hb ^ 1])[i] = 0;
        }
        __syncthreads();
        // phase B: select bin containing the K-th (suffix count crosses K)
        if (tid < 256) {
            int w = tid >> 6;
            for (int j = 0; j < w; ++j) x += wave_sum[j];
            int ge_incl = x;          // count of prefix-matching su with byte >= bin
            int ge_excl = x - hx;     // count with byte > bin
            if (ge_incl >= K && ge_excl < K) {
                s_selbin = bin;
                s_K      = K - ge_excl;
            }
        }
        __syncthreads();
        prefix |= ((unsigned)s_selbin) << shift;
        pmask  |= (0xFFu << shift);
        K = s_K;
        // phase C: histogram next byte over survivors (into hist[hb^1]).
        // During the p==2 scan, survivors ARE the 24-bit-prefix candidates.
        if (p < 3) {
            const int nshift = 24 - 8 * (p + 1);
            for (int q = tid; q < NQ; q += NTM) {
                unsigned u  = su[q];
                bool     pr = ((u & pmask) == prefix);
                if (p == 2 && pr) eqlist[atomicAdd(&s_c24, 1)] = q;
                agg_add(hist[hb ^ 1][wid], (u >> nshift) & 0xFF, pr);
            }
            __syncthreads();
        }
    }
    const unsigned v      = prefix;  // exact bits of TOPK-th largest
    const int      e_take = K;       // how many su==v to take (smallest indices)

    // ---- tie cutoff from candidates: tie q selected iff q < qcut ----
    const int C24 = s_c24;           // 24-bit-prefix matches (small in practice)
    for (int i = tid; i < C24; i += NTM) {
        int q = eqlist[i];
        if (su[q] == v) {
            int r = 0;
            for (int j = 0; j < C24; ++j) {
                int qj = eqlist[j];
                r += (su[qj] == v && qj < q) ? 1 : 0;
            }
            if (r == e_take - 1) s_qcut = q + 1;  // unique writer (indices distinct)
        }
    }
    __syncthreads();
    const int qcut = s_qcut;

    const float s0 = (float)vfs[2 * b];      // reference scales x by vfs[:,0]
    const float s1 = (float)vfs[2 * b + 1];  // and y by vfs[:,1] (quirk replicated)

    // ---- selection + scatter-raster of own slice (~190 boxes) -------------
    const int q0 = part * QSLICE;
    const int q1 = (q0 + QSLICE < NQ) ? (q0 + QSLICE) : NQ;
    for (int q = q0 + tid; q < q1; q += NTM) {
        unsigned u = su[q];
        if (u > v || (u == v && q < qcut)) {
            float4 c4 = coord[(size_t)b * NQ + q];
            float x1 = c4.x - 0.5f * c4.z, y1 = c4.y - 0.5f * c4.w;
            float x2 = c4.x + 0.5f * c4.z, y2 = c4.y + 0.5f * c4.w;
            int lx = (int)floorf(x1 * s0), ly = (int)floorf(y1 * s1);
            int rx = (int)floorf(x2 * s0), ry = (int)floorf(y2 * s1);
            int h0 = ly > 0 ? ly : 0, h1 = ry < FH ? ry : FH;
            int w0 = lx > 0 ? lx : 0, w1 = rx < FW ? rx : FW;
            if (h0 < h1 && w0 < w1) {
                unsigned m[4];
#pragma unroll
                for (int j = 0; j < 4; ++j) {
                    int lo = w0 - 32 * j; lo = lo < 0 ? 0 : lo;
                    int hi = w1 - 32 * j; hi = hi > 32 ? 32 : hi;
                    unsigned mm = 0u;
                    if (hi > lo) {
                        unsigned top = (hi >= 32) ? 0xFFFFFFFFu : ((1u << hi) - 1u);
                        unsigned bot = (lo <= 0) ? 0u : ((1u << lo) - 1u);
                        mm = top & ~bot;
                    }
                    m[j] = mm;
                }
                for (int h = h0; h < h1; ++h) {
#pragma unroll
                    for (int j = 0; j < 4; ++j)
                        if (m[j]) atomicOr(&cov[h * 4 + j], m[j]);
                }
            }
        }
    }
    __syncthreads();

    // ---- dump partial coverage plane ----
    unsigned* dst = pcov + (size_t)(b * NSPLIT + part) * (FH * 4);
    for (int i = tid; i < FH * 4; i += NTM) dst[i] = cov[i];
}

// ---------------- Kernel C: OR partials + fuse padding -> mask (float4) -----
__global__ __launch_bounds__(256) void emit_kernel(const unsigned* __restrict__ pcov,
                                                   const int* __restrict__ vfs,
                                                   float* __restrict__ out) {
    const int idx = blockIdx.x * 256 + threadIdx.x;  // one float4 (4 cells) each
    if (idx >= BS * FH * (FW / 4)) return;
    const int b   = idx / (FH * (FW / 4));
    const int rem = idx - b * (FH * (FW / 4));
    const int h   = rem / (FW / 4);
    const int w4  = rem - h * (FW / 4);
    const int w   = w4 * 4;  // 4-aligned, <100: all 4 bits in one 32-bit word
    const unsigned* p = pcov + (size_t)b * NSPLIT * (FH * 4) + h * 4 + (w >> 5);
    unsigned acc = 0u;
#pragma unroll
    for (int s = 0; s < NSPLIT; ++s) acc |= p[s * (FH * 4)];
    const int  iv0  = vfs[2 * b], iv1 = vfs[2 * b + 1];
    const bool padr = (h >= iv0);
    float4 o;
    o.x = (((acc >> ((w + 0) & 31)) & 1u) && !(padr || (w + 0 >= iv1))) ? 0.0f : -1e20f;
    o.y = (((acc >> ((w + 1) & 31)) & 1u) && !(padr || (w + 1 >= iv1))) ? 0.0f : -1e20f;
    o.z = (((acc >> ((w + 2) & 31)) & 1u) && !(padr || (w + 2 >= iv1))) ? 0.0f : -1e20f;
    o.w = (((acc >> ((w + 3) & 31)) & 1u) && !(padr || (w + 3 >= iv1))) ? 0.0f : -1e20f;
    ((float4*)out)[idx] = o;
}

extern "C" void kernel_launch(void* const* d_in, const int* in_sizes, int n_in,
                              void* d_out, int out_size, void* d_ws, size_t ws_size,
                              hipStream_t stream) {
    const float4* coord = (const float4*)d_in[0];  // (BS, NQ, 4) f32
    const float*  cls   = (const float*)d_in[1];   // (BS, NQ, NC) f32
    const int*    vfs   = (const int*)d_in[2];     // (BS, 2) i32
    // d_in[3] (padding_mask) ignored — recomputed from vfs.
    float*    scores = (float*)d_ws;                           // 768000 B
    unsigned* pcov   = (unsigned*)((char*)d_ws + (size_t)BS * NQ * sizeof(float));
                                                               // 819200 B
    float* out = (float*)d_out;

    const int rows = BS * NQ;  // 192000
    scores_kernel<<<rows / 16, 256, 0, stream>>>((const float4*)cls, scores);
    raster_kernel<<<dim3(NSPLIT, BS), NTM, 0, stream>>>(coord, vfs, scores, pcov);
    const int emit_elems = BS * FH * (FW / 4);     // 160000
    emit_kernel<<<(emit_elems + 255) / 256, 256, 0, stream>>>(pcov, vfs, out);
}

// Round 8
// 298.609 us; speedup vs baseline: 1.0770x; 1.0770x over previous
//
#include <hip/hip_runtime.h>

#define BS   64
#define NQ   3000
#define NC   256
#define FH   100
#define FW   100
#define TOPK 1500

// ---------------- Kernel A: scores[b,q] = max_c class[b,q,c] ----------------
// One row (64 float4) per wave-iteration; 4 rows per wave for 4 outstanding
// loads. Lane l reads float4 l of each row (1 KB coalesced per instruction).
// Memory-bound at ~31 us floor (196.6 MB @ 6.3 TB/s) — at roofline.
__global__ __launch_bounds__(256) void scores_kernel(const float4* __restrict__ cls,
                                                     float* __restrict__ scores) {
    const int tid  = threadIdx.x;
    const int lane = tid & 63;
    const int wave = tid >> 6;
    const int row0 = blockIdx.x * 16 + wave * 4;  // 16 rows per block, grid exact
    const float4* p = cls + (size_t)row0 * (NC / 4) + lane;
    float4 a = p[0], b = p[64], c = p[128], d = p[192];
    float m0 = fmaxf(fmaxf(a.x, a.y), fmaxf(a.z, a.w));
    float m1 = fmaxf(fmaxf(b.x, b.y), fmaxf(b.z, b.w));
    float m2 = fmaxf(fmaxf(c.x, c.y), fmaxf(c.z, c.w));
    float m3 = fmaxf(fmaxf(d.x, d.y), fmaxf(d.z, d.w));
#pragma unroll
    for (int off = 32; off > 0; off >>= 1) {
        m0 = fmaxf(m0, __shfl_xor(m0, off, 64));
        m1 = fmaxf(m1, __shfl_xor(m1, off, 64));
        m2 = fmaxf(m2, __shfl_xor(m2, off, 64));
        m3 = fmaxf(m3, __shfl_xor(m3, off, 64));
    }
    if (lane < 4) {
        float m = (lane == 0) ? m0 : (lane == 1) ? m1 : (lane == 2) ? m2 : m3;
        scores[row0 + lane] = m;
    }
}

// ---------------- Kernel B: per-(batch,slice) select + raster ----------------
// R5 structure — best measured (297.8us). Grid (NSPLIT, BS) = 512 blocks.
// Every block redundantly computes the per-batch threshold (radix descent;
// redundancy runs in parallel on otherwise-idle CUs = free) + scalar tie
// cutoff, then scatter-rasters ONLY its NQ/NSPLIT query slice (~190 boxes)
// into a private LDS bitmap -> partial plane. Design decisions locked by
// measurement: scatter atomicOr beats gather loop (R3 -20us); slice beats
// stripe decomposition (R4 -11us: stripe duplicates box setup 8x); plain
// LDS atomics beat ballot-aggregated software histograms (R6 -24us: the
// hardware's same-address serialization is pipelined and cheap, ~1us total);
// kernel-boundary coherence beats device-scope fences (R2 -100us).
#define NSPLIT 8
#define NTM    512  // 8 waves
#define QSLICE ((NQ + NSPLIT - 1) / NSPLIT)  // 375

__global__ __launch_bounds__(NTM) void raster_kernel(const float4* __restrict__ coord,
                                                     const int* __restrict__ vfs,
                                                     const float* __restrict__ scores,
                                                     unsigned* __restrict__ pcov) {
    __shared__ __align__(16) unsigned su[NQ];  // score bits (positive: uint order == float order)
    __shared__ int      hist[8][256];   // per-wave histograms
    __shared__ unsigned cov[FH * 4];    // 100 rows x 128-bit coverage (this slice)
    __shared__ int      eqlist[NQ];     // 24-bit-prefix candidates from pass 3
    __shared__ int      wave_sum[4];
    __shared__ int      s_selbin, s_K, s_c24, s_qcut;

    const int part = blockIdx.x;       // slice within batch
    const int b    = blockIdx.y;       // batch
    const int tid  = threadIdx.x;
    const int wid  = tid >> 6;

    // vectorized score load: NQ*4B = 12000B, 16B-aligned, 750 uint4
    {
        const uint4* sp = (const uint4*)(scores + b * NQ);
        uint4* sd = (uint4*)su;
        for (int i = tid; i < NQ / 4; i += NTM) sd[i] = sp[i];
    }
    for (int i = tid; i < FH * 4; i += NTM) cov[i] = 0u;
    if (tid == 0) s_c24 = 0;

    // ---- byte-wise radix descent with parallel suffix-scan bin select ----
    unsigned prefix = 0, pmask = 0;
    int K = TOPK;
#pragma unroll
    for (int p = 0; p < 4; ++p) {
        const int shift = 24 - 8 * p;
        for (int i = tid; i < 8 * 256; i += NTM) ((int*)hist)[i] = 0;
        __syncthreads();
        for (int q = tid; q < NQ; q += NTM) {
            unsigned u = su[q];
            if ((u & pmask) == prefix) {
                if (p == 3) eqlist[atomicAdd(&s_c24, 1)] = q;
                atomicAdd(&hist[wid][(u >> shift) & 0xFF], 1);
            }
        }
        __syncthreads();
        // first 256 threads: suffix scan over bins (reversed index = prefix scan)
        int x = 0, hx = 0, bin = 0;
        if (tid < 256) {
            bin = 255 - tid;
            hx = hist[0][bin] + hist[1][bin] + hist[2][bin] + hist[3][bin] +
                 hist[4][bin] + hist[5][bin] + hist[6][bin] + hist[7][bin];
            x = hx;
#pragma unroll
            for (int off = 1; off < 64; off <<= 1) {
                int y = __shfl_up(x, off, 64);
                if ((tid & 63) >= off) x += y;
            }
            if ((tid & 63) == 63) wave_sum[tid >> 6] = x;
        }
        __syncthreads();
        if (tid < 256) {
            int w = tid >> 6;
            for (int j = 0; j < w; ++j) x += wave_sum[j];
            int ge_incl = x;          // count of prefix-matching su with byte >= bin
            int ge_excl = x - hx;     // count with byte > bin
            if (ge_incl >= K && ge_excl < K) {
                s_selbin = bin;
                s_K      = K - ge_excl;
            }
        }
        __syncthreads();
        prefix |= ((unsigned)s_selbin) << shift;
        pmask  |= (0xFFu << shift);
        K = s_K;
        __syncthreads();
    }
    const unsigned v      = prefix;  // exact bits of TOPK-th largest
    const int      e_take = K;       // how many su==v to take (smallest indices)

    // ---- tie cutoff from pass-3 candidates: tie q selected iff q < qcut ----
    const int C24 = s_c24;           // 24-bit-prefix matches (small in practice)
    for (int i = tid; i < C24; i += NTM) {
        int q = eqlist[i];
        if (su[q] == v) {
            int r = 0;
            for (int j = 0; j < C24; ++j) {
                int qj = eqlist[j];
                r += (su[qj] == v && qj < q) ? 1 : 0;
            }
            if (r == e_take - 1) s_qcut = q + 1;  // unique writer (indices distinct)
        }
    }
    __syncthreads();
    const int qcut = s_qcut;

    const float s0 = (float)vfs[2 * b];      // reference scales x by vfs[:,0]
    const float s1 = (float)vfs[2 * b + 1];  // and y by vfs[:,1] (quirk replicated)

    // ---- selection + scatter-raster of own slice (~190 boxes) -------------
    const int q0 = part * QSLICE;
    const int q1 = (q0 + QSLICE < NQ) ? (q0 + QSLICE) : NQ;
    for (int q = q0 + tid; q < q1; q += NTM) {
        unsigned u = su[q];
        if (u > v || (u == v && q < qcut)) {
            float4 c4 = coord[(size_t)b * NQ + q];
            float x1 = c4.x - 0.5f * c4.z, y1 = c4.y - 0.5f * c4.w;
            float x2 = c4.x + 0.5f * c4.z, y2 = c4.y + 0.5f * c4.w;
            int lx = (int)floorf(x1 * s0), ly = (int)floorf(y1 * s1);
            int rx = (int)floorf(x2 * s0), ry = (int)floorf(y2 * s1);
            int h0 = ly > 0 ? ly : 0, h1 = ry < FH ? ry : FH;
            int w0 = lx > 0 ? lx : 0, w1 = rx < FW ? rx : FW;
            if (h0 < h1 && w0 < w1) {
                unsigned m[4];
#pragma unroll
                for (int j = 0; j < 4; ++j) {
                    int lo = w0 - 32 * j; lo = lo < 0 ? 0 : lo;
                    int hi = w1 - 32 * j; hi = hi > 32 ? 32 : hi;
                    unsigned mm = 0u;
                    if (hi > lo) {
                        unsigned top = (hi >= 32) ? 0xFFFFFFFFu : ((1u << hi) - 1u);
                        unsigned bot = (lo <= 0) ? 0u : ((1u << lo) - 1u);
                        mm = top & ~bot;
                    }
                    m[j] = mm;
                }
                for (int h = h0; h < h1; ++h) {
#pragma unroll
                    for (int j = 0; j < 4; ++j)
                        if (m[j]) atomicOr(&cov[h * 4 + j], m[j]);
                }
            }
        }
    }
    __syncthreads();

    // ---- dump partial coverage plane ----
    unsigned* dst = pcov + (size_t)(b * NSPLIT + part) * (FH * 4);
    for (int i = tid; i < FH * 4; i += NTM) dst[i] = cov[i];
}

// ---------------- Kernel C: OR partials + fuse padding -> mask (float4) -----
__global__ __launch_bounds__(256) void emit_kernel(const unsigned* __restrict__ pcov,
                                                   const int* __restrict__ vfs,
                                                   float* __restrict__ out) {
    const int idx = blockIdx.x * 256 + threadIdx.x;  // one float4 (4 cells) each
    if (idx >= BS * FH * (FW / 4)) return;
    const int b   = idx / (FH * (FW / 4));
    const int rem = idx - b * (FH * (FW / 4));
    const int h   = rem / (FW / 4);
    const int w4  = rem - h * (FW / 4);
    const int w   = w4 * 4;  // 4-aligned, <100: all 4 bits in one 32-bit word
    const unsigned* p = pcov + (size_t)b * NSPLIT * (FH * 4) + h * 4 + (w >> 5);
    unsigned acc = 0u;
#pragma unroll
    for (int s = 0; s < NSPLIT; ++s) acc |= p[s * (FH * 4)];
    const int  iv0  = vfs[2 * b], iv1 = vfs[2 * b + 1];
    const bool padr = (h >= iv0);
    float4 o;
    o.x = (((acc >> ((w + 0) & 31)) & 1u) && !(padr || (w + 0 >= iv1))) ? 0.0f : -1e20f;
    o.y = (((acc >> ((w + 1) & 31)) & 1u) && !(padr || (w + 1 >= iv1))) ? 0.0f : -1e20f;
    o.z = (((acc >> ((w + 2) & 31)) & 1u) && !(padr || (w + 2 >= iv1))) ? 0.0f : -1e20f;
    o.w = (((acc >> ((w + 3) & 31)) & 1u) && !(padr || (w + 3 >= iv1))) ? 0.0f : -1e20f;
    ((float4*)out)[idx] = o;
}

extern "C" void kernel_launch(void* const* d_in, const int* in_sizes, int n_in,
                              void* d_out, int out_size, void* d_ws, size_t ws_size,
                              hipStream_t stream) {
    const float4* coord = (const float4*)d_in[0];  // (BS, NQ, 4) f32
    const float*  cls   = (const float*)d_in[1];   // (BS, NQ, NC) f32
    const int*    vfs   = (const int*)d_in[2];     // (BS, 2) i32
    // d_in[3] (padding_mask) ignored — recomputed from vfs.
    float*    scores = (float*)d_ws;                           // 768000 B
    unsigned* pcov   = (unsigned*)((char*)d_ws + (size_t)BS * NQ * sizeof(float));
                                                               // 819200 B
    float* out = (float*)d_out;

    const int rows = BS * NQ;  // 192000
    scores_kernel<<<rows / 16, 256, 0, stream>>>((const float4*)cls, scores);
    raster_kernel<<<dim3(NSPLIT, BS), NTM, 0, stream>>>(coord, vfs, scores, pcov);
    const int emit_elems = BS * FH * (FW / 4);     // 160000
    emit_kernel<<<(emit_elems + 255) / 256, 256, 0, stream>>>(pcov, vfs, out);
}